// Round 4
// baseline (339.040 us; speedup 1.0000x reference)
//
#include <hip/hip_runtime.h>

#define D_IN 128

typedef unsigned short u16;
typedef __attribute__((ext_vector_type(8))) short short8;
typedef __attribute__((ext_vector_type(4))) float f32x4;

static inline size_t align_up(size_t v, size_t a) { return (v + a - 1) & ~(a - 1); }

__device__ inline u16 f2bf(float f) {
    union { float f; unsigned int u; } c; c.f = f;
    unsigned int u = c.u;
    return (u16)((u + 0x7fffu + ((u >> 16) & 1u)) >> 16);   // RNE
}
__device__ inline float bflo(unsigned int u) {
    union { unsigned int u; float f; } c; c.u = u << 16; return c.f;
}
__device__ inline float bfhi(unsigned int u) {
    union { unsigned int u; float f; } c; c.u = u & 0xffff0000u; return c.f;
}
__device__ inline unsigned int packbf2(float lo, float hi) {
    return (unsigned int)f2bf(lo) | ((unsigned int)f2bf(hi) << 16);
}

#define GLDS16(gp, lp) \
    __builtin_amdgcn_global_load_lds((const __attribute__((address_space(1))) void*)(gp), \
                                     (__attribute__((address_space(3))) void*)(lp), 16, 0, 0)

// ---------------- prep: zero deg + cast x->bf16 + pack weights (independent ranges) ----------------
__global__ void k_prep(const float* __restrict__ x, u16* __restrict__ xb, int total4,
                       int* __restrict__ deg, int n,
                       const float* __restrict__ Ws1, const float* __restrict__ Wn1,
                       const float* __restrict__ Ws2, const float* __restrict__ Wn2,
                       u16* __restrict__ W1t, u16* __restrict__ W2t) {
    int i = blockIdx.x * blockDim.x + threadIdx.x;
    if (i < total4) {
        float4 v = ((const float4*)x)[i];
        uint2 o;
        o.x = packbf2(v.x, v.y);
        o.y = packbf2(v.z, v.w);
        *(uint2*)&xb[(size_t)i * 4] = o;
    }
    if (i < n) deg[i] = 0;
    if (i < 128 * 256) {
        int nn = i >> 8, kk = i & 255;
        float v = (kk < 128) ? Ws1[kk * 128 + nn] : Wn1[(kk - 128) * 128 + nn];
        W1t[i] = f2bf(v);
    }
    if (i < 128 * 128) {
        int nn = i >> 7, kk = i & 127;
        float v = (nn < 64) ? Ws2[kk * 64 + nn] : Wn2[kk * 64 + (nn - 64)];
        W2t[i] = f2bf(v);
    }
}

// ---------------- degree histogram (no-return atomics) ----------------
__global__ void k_hist(const int* __restrict__ dst, int* __restrict__ deg, int e) {
    int i = blockIdx.x * blockDim.x + threadIdx.x;
    if (i < e) atomicAdd(&deg[dst[i]], 1);
}

// ---------------- scan 1: per-block (1024 elems) exclusive scan + block sums ----------------
__global__ void k_scan1(const int* __restrict__ deg, int* __restrict__ rs,
                        int* __restrict__ bsum, int n) {
    __shared__ int sd[256];
    int t = threadIdx.x;
    int base = blockIdx.x * 1024 + t * 4;
    int v[4]; int s = 0;
    #pragma unroll
    for (int j = 0; j < 4; ++j) { v[j] = (base + j < n) ? deg[base + j] : 0; s += v[j]; }
    sd[t] = s;
    __syncthreads();
    #pragma unroll
    for (int off = 1; off < 256; off <<= 1) {
        int x = (t >= off) ? sd[t - off] : 0;
        __syncthreads();
        sd[t] += x;
        __syncthreads();
    }
    int run = sd[t] - s;   // exclusive prefix of this thread's chunk
    #pragma unroll
    for (int j = 0; j < 4; ++j) {
        if (base + j < n) rs[base + j] = run;
        run += v[j];
    }
    if (t == 255) bsum[blockIdx.x] = sd[255];
}

// ---------------- scan 2: single block, exclusive scan of block sums ----------------
__global__ void k_scan2(int* __restrict__ bsum, int nb) {
    __shared__ int sd[128];
    int t = threadIdx.x;           // 128 threads, nb <= 128
    int own = (t < nb) ? bsum[t] : 0;
    sd[t] = own;
    __syncthreads();
    #pragma unroll
    for (int off = 1; off < 128; off <<= 1) {
        int x = (t >= off) ? sd[t - off] : 0;
        __syncthreads();
        sd[t] += x;
        __syncthreads();
    }
    if (t < nb) bsum[t] = sd[t] - own;   // exclusive
}

// ---------------- scan 3: add block offsets, copy to bump cursors ----------------
__global__ void k_scan3(int* __restrict__ rs, const int* __restrict__ bsum,
                        int* __restrict__ cur, int n) {
    int i = blockIdx.x * blockDim.x + threadIdx.x;
    if (i >= n) return;
    int v = rs[i] + bsum[i >> 10];
    rs[i] = v;
    cur[i] = v;
}

// ---------------- placement into compact CSR ----------------
__global__ void k_place(const int* __restrict__ src, const int* __restrict__ dst,
                        int* __restrict__ cur, int* __restrict__ csr, int e) {
    int i = blockIdx.x * blockDim.x + threadIdx.x;
    if (i >= e) return;
    int d = dst[i];
    int pos = atomicAdd(&cur[d], 1);
    csr[pos] = src[i];
}

// ---------------- layer-1 gather-aggregate (bf16 rows, fp32 accum, bf16 out) ----------------
// one wave per node; 16 lanes x 16B cover 128-bf16 row; 4 quads x 2-deep pipelined neighbor loop
__global__ void k_agg1(const u16* __restrict__ xb, const int* __restrict__ rs,
                       const int* __restrict__ cur, const int* __restrict__ csr,
                       u16* __restrict__ hnb, int n) {
    int wid = (blockIdx.x * blockDim.x + threadIdx.x) >> 6;
    int lane = threadIdx.x & 63;
    if (wid >= n) return;
    int chunk = lane & 15;
    int quad = lane >> 4;
    int start = rs[wid];
    int deg = cur[wid] - start;
    float inv = 1.0f / (1.0f + (float)deg);
    const int* nb = csr + start;
    float acc[8] = {};
    int k = quad;
    for (; k + 4 < deg; k += 8) {
        int s0 = nb[k], s1 = nb[k + 4];
        uint4 u0 = *(const uint4*)(xb + (size_t)s0 * 128 + chunk * 8);
        uint4 u1 = *(const uint4*)(xb + (size_t)s1 * 128 + chunk * 8);
        acc[0] += bflo(u0.x); acc[1] += bfhi(u0.x);
        acc[2] += bflo(u0.y); acc[3] += bfhi(u0.y);
        acc[4] += bflo(u0.z); acc[5] += bfhi(u0.z);
        acc[6] += bflo(u0.w); acc[7] += bfhi(u0.w);
        acc[0] += bflo(u1.x); acc[1] += bfhi(u1.x);
        acc[2] += bflo(u1.y); acc[3] += bfhi(u1.y);
        acc[4] += bflo(u1.z); acc[5] += bfhi(u1.z);
        acc[6] += bflo(u1.w); acc[7] += bfhi(u1.w);
    }
    if (k < deg) {
        int s = nb[k];
        uint4 u = *(const uint4*)(xb + (size_t)s * 128 + chunk * 8);
        acc[0] += bflo(u.x); acc[1] += bfhi(u.x);
        acc[2] += bflo(u.y); acc[3] += bfhi(u.y);
        acc[4] += bflo(u.z); acc[5] += bfhi(u.z);
        acc[6] += bflo(u.w); acc[7] += bfhi(u.w);
    }
    #pragma unroll
    for (int t = 0; t < 8; ++t) {
        acc[t] += __shfl_xor(acc[t], 16);
        acc[t] += __shfl_xor(acc[t], 32);
    }
    if (quad == 0) {
        uint4 u = *(const uint4*)(xb + (size_t)wid * 128 + chunk * 8);  // self
        acc[0] += bflo(u.x); acc[1] += bfhi(u.x);
        acc[2] += bflo(u.y); acc[3] += bfhi(u.y);
        acc[4] += bflo(u.z); acc[5] += bfhi(u.z);
        acc[6] += bflo(u.w); acc[7] += bfhi(u.w);
        uint4 o;
        o.x = packbf2(acc[0] * inv, acc[1] * inv);
        o.y = packbf2(acc[2] * inv, acc[3] * inv);
        o.z = packbf2(acc[4] * inv, acc[5] * inv);
        o.w = packbf2(acc[6] * inv, acc[7] * inv);
        *(uint4*)(hnb + (size_t)wid * 128 + chunk * 8) = o;
    }
}

// ---------------- MFMA GEMM1: h1b = relu([xb|hnb] @ W1cat + b1), bf16 out ----------------
__launch_bounds__(256)
__global__ void k_gemm1_mfma(const u16* __restrict__ xb, const u16* hnb,
                             const u16* __restrict__ W1t, const float* __restrict__ b1,
                             u16* h1b, int n) {
    __shared__ u16 As[128 * 32];
    __shared__ u16 Bs[128 * 32];
    int tid = threadIdx.x;
    int lane = tid & 63;
    int wave = tid >> 6;
    int wr = wave >> 1, wc = wave & 1;
    int row0 = blockIdx.x * 128;
    int srow = tid >> 2;
    int scol = (tid & 3) * 8;
    int m = lane & 15;
    int q = lane >> 4;

    f32x4 zero = {0.f, 0.f, 0.f, 0.f};
    f32x4 acc[4][4];
    #pragma unroll
    for (int i = 0; i < 4; ++i)
        #pragma unroll
        for (int j = 0; j < 4; ++j) acc[i][j] = zero;

    for (int kb = 0; kb < 8; ++kb) {
        const u16* Asrc = (kb < 4) ? xb : hnb;
        int kbase = (kb & 3) * 32;
        int krowB = kb * 32;
        #pragma unroll
        for (int t = 0; t < 2; ++t) {
            int gr = row0 + t * 64 + srow;
            if (gr >= n) gr = n - 1;
            GLDS16(Asrc + (size_t)gr * 128 + kbase + scol, As + t * 2048 + wave * 512);
        }
        #pragma unroll
        for (int t = 0; t < 2; ++t) {
            int nn = t * 64 + srow;
            GLDS16(W1t + (size_t)nn * 256 + krowB + scol, Bs + t * 2048 + wave * 512);
        }
        __syncthreads();
        #pragma unroll
        for (int i = 0; i < 4; ++i) {
            short8 a = *(const short8*)&As[(wr * 64 + i * 16 + m) * 32 + q * 8];
            #pragma unroll
            for (int j = 0; j < 4; ++j) {
                short8 b = *(const short8*)&Bs[(wc * 64 + j * 16 + m) * 32 + q * 8];
                acc[i][j] = __builtin_amdgcn_mfma_f32_16x16x32_bf16(a, b, acc[i][j], 0, 0, 0);
            }
        }
        __syncthreads();
    }
    #pragma unroll
    for (int i = 0; i < 4; ++i) {
        int grow = row0 + wr * 64 + i * 16 + q * 4;
        #pragma unroll
        for (int j = 0; j < 4; ++j) {
            int col = wc * 64 + j * 16 + m;
            float bias = b1[col];
            #pragma unroll
            for (int r = 0; r < 4; ++r) {
                int gr = grow + r;
                if (gr < n) h1b[(size_t)gr * 128 + col] = f2bf(fmaxf(acc[i][j][r] + bias, 0.f));
            }
        }
    }
}

// ---------------- MFMA GEMM2: qp = h1b @ [Ws2|Wn2] (cols 0..63=q, 64..127=p) ----------------
__launch_bounds__(256)
__global__ void k_gemm2_mfma(const u16* __restrict__ h1b, const u16* __restrict__ W2t,
                             u16* __restrict__ qp, int n) {
    __shared__ u16 As[128 * 32];
    __shared__ u16 Bs[128 * 32];
    int tid = threadIdx.x;
    int lane = tid & 63;
    int wave = tid >> 6;
    int wr = wave >> 1, wc = wave & 1;
    int row0 = blockIdx.x * 128;
    int srow = tid >> 2;
    int scol = (tid & 3) * 8;
    int m = lane & 15;
    int q = lane >> 4;

    f32x4 zero = {0.f, 0.f, 0.f, 0.f};
    f32x4 acc[4][4];
    #pragma unroll
    for (int i = 0; i < 4; ++i)
        #pragma unroll
        for (int j = 0; j < 4; ++j) acc[i][j] = zero;

    for (int kb = 0; kb < 4; ++kb) {
        int kbase = kb * 32;
        #pragma unroll
        for (int t = 0; t < 2; ++t) {
            int gr = row0 + t * 64 + srow;
            if (gr >= n) gr = n - 1;
            GLDS16(h1b + (size_t)gr * 128 + kbase + scol, As + t * 2048 + wave * 512);
        }
        #pragma unroll
        for (int t = 0; t < 2; ++t) {
            int nn = t * 64 + srow;
            GLDS16(W2t + (size_t)nn * 128 + kbase + scol, Bs + t * 2048 + wave * 512);
        }
        __syncthreads();
        #pragma unroll
        for (int i = 0; i < 4; ++i) {
            short8 a = *(const short8*)&As[(wr * 64 + i * 16 + m) * 32 + q * 8];
            #pragma unroll
            for (int j = 0; j < 4; ++j) {
                short8 b = *(const short8*)&Bs[(wc * 64 + j * 16 + m) * 32 + q * 8];
                acc[i][j] = __builtin_amdgcn_mfma_f32_16x16x32_bf16(a, b, acc[i][j], 0, 0, 0);
            }
        }
        __syncthreads();
    }
    #pragma unroll
    for (int i = 0; i < 4; ++i) {
        int grow = row0 + wr * 64 + i * 16 + q * 4;
        #pragma unroll
        for (int j = 0; j < 4; ++j) {
            int col = wc * 64 + j * 16 + m;
            #pragma unroll
            for (int r = 0; r < 4; ++r) {
                int gr = grow + r;
                if (gr < n) qp[(size_t)gr * 128 + col] = f2bf(acc[i][j][r]);
            }
        }
    }
}

// ---------------- layer-2 gather-aggregate + epilogue ----------------
__global__ void k_agg2(const u16* __restrict__ qp, const int* __restrict__ rs,
                       const int* __restrict__ cur, const int* __restrict__ csr,
                       const float* __restrict__ b2, float* __restrict__ out, int n) {
    int wid = (blockIdx.x * blockDim.x + threadIdx.x) >> 6;
    int lane = threadIdx.x & 63;
    if (wid >= n) return;
    int chunk = lane & 7;
    int oct = lane >> 3;
    int start = rs[wid];
    int deg = cur[wid] - start;
    float inv = 1.0f / (1.0f + (float)deg);
    const int* nb = csr + start;
    float acc[8] = {};
    for (int k = oct; k < deg; k += 8) {
        int s = nb[k];
        uint4 u = *(const uint4*)(qp + (size_t)s * 128 + 64 + chunk * 8);
        acc[0] += bflo(u.x); acc[1] += bfhi(u.x);
        acc[2] += bflo(u.y); acc[3] += bfhi(u.y);
        acc[4] += bflo(u.z); acc[5] += bfhi(u.z);
        acc[6] += bflo(u.w); acc[7] += bfhi(u.w);
    }
    #pragma unroll
    for (int t = 0; t < 8; ++t) {
        acc[t] += __shfl_xor(acc[t], 8);
        acc[t] += __shfl_xor(acc[t], 16);
        acc[t] += __shfl_xor(acc[t], 32);
    }
    if (oct == 0) {
        uint4 up = *(const uint4*)(qp + (size_t)wid * 128 + 64 + chunk * 8); // self p
        uint4 uq = *(const uint4*)(qp + (size_t)wid * 128 + chunk * 8);      // q
        float o[8];
        o[0] = (acc[0] + bflo(up.x)) * inv + bflo(uq.x);
        o[1] = (acc[1] + bfhi(up.x)) * inv + bfhi(uq.x);
        o[2] = (acc[2] + bflo(up.y)) * inv + bflo(uq.y);
        o[3] = (acc[3] + bfhi(up.y)) * inv + bfhi(uq.y);
        o[4] = (acc[4] + bflo(up.z)) * inv + bflo(uq.z);
        o[5] = (acc[5] + bfhi(up.z)) * inv + bfhi(uq.z);
        o[6] = (acc[6] + bflo(up.w)) * inv + bflo(uq.w);
        o[7] = (acc[7] + bfhi(up.w)) * inv + bfhi(uq.w);
        float* op = out + (size_t)wid * 64 + chunk * 8;
        const float* bp = b2 + chunk * 8;
        *(float4*)(op + 0) = make_float4(o[0] + bp[0], o[1] + bp[1], o[2] + bp[2], o[3] + bp[3]);
        *(float4*)(op + 4) = make_float4(o[4] + bp[4], o[5] + bp[5], o[6] + bp[6], o[7] + bp[7]);
    }
}

extern "C" void kernel_launch(void* const* d_in, const int* in_sizes, int n_in,
                              void* d_out, int out_size, void* d_ws, size_t ws_size,
                              hipStream_t stream) {
    const float* x   = (const float*)d_in[0];
    const int*   src = (const int*)d_in[1];
    const int*   dst = (const int*)d_in[2];
    const float* Ws1 = (const float*)d_in[3];
    const float* Wn1 = (const float*)d_in[4];
    const float* b1  = (const float*)d_in[5];
    const float* Ws2 = (const float*)d_in[6];
    const float* Wn2 = (const float*)d_in[7];
    const float* b2  = (const float*)d_in[8];
    int n = in_sizes[0] / D_IN;
    int e = in_sizes[1];

    char* ws = (char*)d_ws;
    size_t off = 0;
    int* deg  = (int*)(ws + off); off = align_up(off + (size_t)n * 4, 256);
    int* rs   = (int*)(ws + off); off = align_up(off + (size_t)n * 4, 256);
    int* cur  = (int*)(ws + off); off = align_up(off + (size_t)n * 4, 256);
    int* bsum = (int*)(ws + off); off = align_up(off + 128 * 4, 256);
    int* csr  = (int*)(ws + off); off = align_up(off + (size_t)e * 4, 256);
    u16* xb   = (u16*)(ws + off); off = align_up(off + (size_t)n * 128 * 2, 256);
    u16* hnb  = (u16*)(ws + off); off = align_up(off + (size_t)n * 128 * 2, 256);
    u16* qp   = (u16*)(ws + off); off = align_up(off + (size_t)n * 128 * 2, 256);
    u16* W1t  = (u16*)(ws + off); off = align_up(off + (size_t)128 * 256 * 2, 256);
    u16* W2t  = (u16*)(ws + off); off = align_up(off + (size_t)128 * 128 * 2, 256);
    u16* h1b = hnb;   // safe alias: gemm1 reads/writes only its own block rows
    float* outp = (float*)d_out;

    const int B = 256;
    int nblk_scan = (n + 1023) / 1024;   // <= 128
    k_prep<<<(n * 32 + B - 1) / B, B, 0, stream>>>(x, xb, n * 32, deg, n,
                                                   Ws1, Wn1, Ws2, Wn2, W1t, W2t);
    k_hist<<<(e + B - 1) / B, B, 0, stream>>>(dst, deg, e);
    k_scan1<<<nblk_scan, 256, 0, stream>>>(deg, rs, bsum, n);
    k_scan2<<<1, 128, 0, stream>>>(bsum, nblk_scan);
    k_scan3<<<(n + B - 1) / B, B, 0, stream>>>(rs, bsum, cur, n);
    k_place<<<(e + B - 1) / B, B, 0, stream>>>(src, dst, cur, csr, e);
    k_agg1<<<(n + 3) / 4, B, 0, stream>>>(xb, rs, cur, csr, hnb, n);
    k_gemm1_mfma<<<(n + 127) / 128, 256, 0, stream>>>(xb, hnb, W1t, b1, h1b, n);
    k_gemm2_mfma<<<(n + 127) / 128, 256, 0, stream>>>(h1b, W2t, qp, n);
    k_agg2<<<(n + 3) / 4, B, 0, stream>>>(qp, rs, cur, csr, b2, outp, n);
}